// Round 1
// baseline (84.294 us; speedup 1.0000x reference)
//
#include <hip/hip_runtime.h>

typedef __attribute__((ext_vector_type(8))) short bf16x8;
typedef __attribute__((ext_vector_type(4))) float f32x4;

#define GAMMA_ 0.5f
#define LOG2E_ 1.4426950408889634f

constexpr int D      = 256;   // feature dim
constexpr int BM     = 64;    // rows of X per block
constexpr int BN     = 64;    // cols (X_train rows) per j-tile
constexpr int JSPLIT = 16;    // split of M across blockIdx.y (atomic partials)

// ---------- helpers ----------
__device__ __forceinline__ unsigned short f2bf(float f) {
    unsigned int x = __float_as_uint(f);
    x += 0x7FFFu + ((x >> 16) & 1u);          // round-to-nearest-even
    return (unsigned short)(x >> 16);
}

// ---------- prep: fp32 -> bf16, row sum-of-squares, dual coefs ----------
__global__ void prep_kernel(const float* __restrict__ src,
                            unsigned short* __restrict__ dst,
                            float* __restrict__ srow,
                            const float* __restrict__ alphas,
                            const float* __restrict__ y,
                            float* __restrict__ coef,
                            int rows) {
    int w = threadIdx.x >> 6;         // wave id: one wave per row
    int l = threadIdx.x & 63;
    int row = blockIdx.x * 4 + w;
    if (row >= rows) return;
    const float4 v = reinterpret_cast<const float4*>(src + (size_t)row * D)[l];
    ushort4 u;
    u.x = f2bf(v.x); u.y = f2bf(v.y); u.z = f2bf(v.z); u.w = f2bf(v.w);
    reinterpret_cast<ushort4*>(dst + (size_t)row * D)[l] = u;
    float ss = v.x * v.x + v.y * v.y + v.z * v.z + v.w * v.w;
    #pragma unroll
    for (int off = 32; off >= 1; off >>= 1) ss += __shfl_xor(ss, off);
    if (l == 0) {
        srow[row] = -GAMMA_ * LOG2E_ * ss;    // folded into exp2 argument
        if (coef != nullptr) coef[row] = alphas[row] * y[row];
    }
}

__global__ void init_out_kernel(float* __restrict__ out,
                                const float* __restrict__ b, int n) {
    int i = blockIdx.x * 256 + threadIdx.x;
    if (i < n) out[i] = b[0];
}

// ---------- fused RBF-SVM predict ----------
// pred_i = sum_j exp2( s_i + t_j + (2*gamma*log2e) * <x_i, xt_j> ) * coef_j + b
__launch_bounds__(256)
__global__ void svm_main_kernel(const unsigned short* __restrict__ Abf,
                                const unsigned short* __restrict__ Bbf,
                                const float* __restrict__ srow,
                                const float* __restrict__ tcol,
                                const float* __restrict__ coef,
                                float* __restrict__ out,
                                int M) {
    __shared__ short As[BM * D];   // 32 KiB, XOR-swizzled
    __shared__ short Bs[BN * D];   // 32 KiB, XOR-swizzled

    const int tid = threadIdx.x;
    const int w   = tid >> 6;          // wave 0..3
    const int l   = tid & 63;
    const int wr  = w >> 1;            // 2x2 wave grid
    const int wc  = w & 1;
    const int row0  = blockIdx.x * BM;
    const int jspan = M / JSPLIT;      // 512
    const int jbase = blockIdx.y * jspan;

    // ---- stage A once (64x256 bf16 = 32KB), swizzled ----
    {
        const char* g = (const char*)(Abf + (size_t)row0 * D);
        char* lds = (char*)As;
        #pragma unroll
        for (int c = 0; c < 8; ++c) {
            int byteoff = (c * 256 + tid) * 16;
            int row = byteoff >> 9;                      // 512 B per row
            int sw  = byteoff ^ ((row & 7) << 4);
            *(int4*)(lds + sw) = *(const int4*)(g + byteoff);
        }
    }

    // per-lane row constants: row = row0 + wr*32 + mi*16 + (l>>4)*4 + r
    float sreg[2][4];
    #pragma unroll
    for (int mi = 0; mi < 2; ++mi)
        #pragma unroll
        for (int r = 0; r < 4; ++r)
            sreg[mi][r] = srow[row0 + wr * 32 + mi * 16 + (l >> 4) * 4 + r];

    float partial[2][4];
    #pragma unroll
    for (int mi = 0; mi < 2; ++mi)
        #pragma unroll
        for (int r = 0; r < 4; ++r) partial[mi][r] = 0.0f;

    const float K2G = 2.0f * GAMMA_ * LOG2E_;
    const int JT = jspan / BN;   // 8 j-tiles per block

    for (int jt = 0; jt < JT; ++jt) {
        __syncthreads();   // previous tile's LDS reads done before overwrite
        {   // ---- stage B tile (64x256 bf16 = 32KB), swizzled ----
            const char* g = (const char*)(Bbf + (size_t)(jbase + jt * BN) * D);
            char* lds = (char*)Bs;
            #pragma unroll
            for (int c = 0; c < 8; ++c) {
                int byteoff = (c * 256 + tid) * 16;
                int row = byteoff >> 9;
                int sw  = byteoff ^ ((row & 7) << 4);
                *(int4*)(lds + sw) = *(const int4*)(g + byteoff);
            }
        }
        __syncthreads();

        // ---- MFMA over K = 256 (8 steps of 32) ----
        f32x4 acc[2][2];
        #pragma unroll
        for (int mi = 0; mi < 2; ++mi)
            #pragma unroll
            for (int ni = 0; ni < 2; ++ni) {
                f32x4 z = {0.f, 0.f, 0.f, 0.f};
                acc[mi][ni] = z;
            }

        #pragma unroll
        for (int ks = 0; ks < 8; ++ks) {
            const int kb = ks * 64;   // byte offset of this K chunk (32 bf16)
            bf16x8 a[2], b[2];
            #pragma unroll
            for (int mi = 0; mi < 2; ++mi) {
                int row = wr * 32 + mi * 16 + (l & 15);
                int byteoff = row * 512 + kb + ((l >> 4) * 16);
                int sw = byteoff ^ ((row & 7) << 4);
                a[mi] = *(const bf16x8*)((const char*)As + sw);
            }
            #pragma unroll
            for (int ni = 0; ni < 2; ++ni) {
                int col = wc * 32 + ni * 16 + (l & 15);
                int byteoff = col * 512 + kb + ((l >> 4) * 16);
                int sw = byteoff ^ ((col & 7) << 4);
                b[ni] = *(const bf16x8*)((const char*)Bs + sw);
            }
            #pragma unroll
            for (int mi = 0; mi < 2; ++mi)
                #pragma unroll
                for (int ni = 0; ni < 2; ++ni)
                    acc[mi][ni] = __builtin_amdgcn_mfma_f32_16x16x32_bf16(
                        a[mi], b[ni], acc[mi][ni], 0, 0, 0);
        }

        // ---- fused epilogue: exp + weighted row-accumulate ----
        #pragma unroll
        for (int ni = 0; ni < 2; ++ni) {
            int colg = jbase + jt * BN + wc * 32 + ni * 16 + (l & 15);
            float t  = tcol[colg];
            float cf = coef[colg];
            #pragma unroll
            for (int mi = 0; mi < 2; ++mi) {
                #pragma unroll
                for (int r = 0; r < 4; ++r) {
                    float arg = fmaf(acc[mi][ni][r], K2G, sreg[mi][r] + t);
                    float p = __builtin_amdgcn_exp2f(arg);
                    partial[mi][r] = fmaf(p, cf, partial[mi][r]);
                }
            }
        }
    }

    // ---- reduce across the 16 lanes of each row group, then atomicAdd ----
    #pragma unroll
    for (int mi = 0; mi < 2; ++mi) {
        #pragma unroll
        for (int r = 0; r < 4; ++r) {
            float v = partial[mi][r];
            v += __shfl_xor(v, 1);
            v += __shfl_xor(v, 2);
            v += __shfl_xor(v, 4);
            v += __shfl_xor(v, 8);
            if ((l & 15) == 0) {
                int rowg = row0 + wr * 32 + mi * 16 + (l >> 4) * 4 + r;
                atomicAdd(&out[rowg], v);
            }
        }
    }
}

// ---------- launcher ----------
extern "C" void kernel_launch(void* const* d_in, const int* in_sizes, int n_in,
                              void* d_out, int out_size, void* d_ws, size_t ws_size,
                              hipStream_t stream) {
    const float* X      = (const float*)d_in[0];
    const float* Xt     = (const float*)d_in[1];
    const float* alphas = (const float*)d_in[2];
    const float* y      = (const float*)d_in[3];
    const float* b      = (const float*)d_in[4];
    float* out = (float*)d_out;

    const int N = in_sizes[0] / D;   // 8192
    const int M = in_sizes[1] / D;   // 8192

    // workspace layout: bf16 X | bf16 Xt | srow[N] | tcol[M] | coef[M]
    char* ws = (char*)d_ws;
    unsigned short* Abf = (unsigned short*)ws;
    unsigned short* Bbf = Abf + (size_t)N * D;
    float* srow = (float*)(Bbf + (size_t)M * D);
    float* tcol = srow + N;
    float* coef = tcol + M;

    prep_kernel<<<N / 4, 256, 0, stream>>>(X,  Abf, srow, nullptr, nullptr, nullptr, N);
    prep_kernel<<<M / 4, 256, 0, stream>>>(Xt, Bbf, tcol, alphas, y, coef, M);
    init_out_kernel<<<(N + 255) / 256, 256, 0, stream>>>(out, b, N);

    dim3 grid(N / BM, JSPLIT);
    svm_main_kernel<<<grid, 256, 0, stream>>>(Abf, Bbf, srow, tcol, coef, out, M);
}

// Round 2
// 55.821 us; speedup vs baseline: 1.5101x; 1.5101x over previous
//
#include <hip/hip_runtime.h>

typedef __attribute__((ext_vector_type(8))) short bf16x8;
typedef __attribute__((ext_vector_type(4))) float f32x4;

#define GAMMA_ 0.5f
#define LOG2E_ 1.4426950408889634f

constexpr int D      = 256;   // feature dim
constexpr int BM     = 128;   // rows of X per block
constexpr int BN     = 128;   // X_train rows per j-tile
constexpr int BK     = 64;    // K-chunk staged per step (B tile)
constexpr int JSPLIT = 16;    // split of M across blockIdx.y

// ---------- helpers ----------
__device__ __forceinline__ unsigned short f2bf(float f) {
    unsigned int x = __float_as_uint(f);
    x += 0x7FFFu + ((x >> 16) & 1u);          // RNE
    return (unsigned short)(x >> 16);
}

__device__ __forceinline__ void gload16(void* lds, const void* g) {
    __builtin_amdgcn_global_load_lds(
        (const __attribute__((address_space(1))) void*)g,
        (__attribute__((address_space(3))) void*)lds, 16, 0, 0);
}

// ---------- prep: cast to bf16, row |x|^2, coefs, out-init ----------
__global__ void prep_all_kernel(const float* __restrict__ X,
                                const float* __restrict__ Xt,
                                const float* __restrict__ alphas,
                                const float* __restrict__ y,
                                const float* __restrict__ b,
                                unsigned short* __restrict__ Abf,
                                unsigned short* __restrict__ Bbf,
                                float* __restrict__ srow,
                                float* __restrict__ tcol,
                                float* __restrict__ coef,
                                float* __restrict__ out,
                                int N, int M) {
    int w = threadIdx.x >> 6;         // one wave per row
    int l = threadIdx.x & 63;
    int row = blockIdx.x * 4 + w;
    if (row >= N + M) return;
    const float* src;
    unsigned short* dst;
    if (row < N) { src = X  + (size_t)row * D;       dst = Abf + (size_t)row * D; }
    else         { src = Xt + (size_t)(row - N) * D; dst = Bbf + (size_t)(row - N) * D; }
    const float4 v = reinterpret_cast<const float4*>(src)[l];
    ushort4 u;
    u.x = f2bf(v.x); u.y = f2bf(v.y); u.z = f2bf(v.z); u.w = f2bf(v.w);
    reinterpret_cast<ushort4*>(dst)[l] = u;
    float ss = v.x * v.x + v.y * v.y + v.z * v.z + v.w * v.w;
    #pragma unroll
    for (int off = 32; off >= 1; off >>= 1) ss += __shfl_xor(ss, off);
    if (l == 0) {
        float folded = -GAMMA_ * LOG2E_ * ss;
        if (row < N) { srow[row] = folded; out[row] = b[0]; }
        else {
            int r2 = row - N;
            tcol[r2] = folded;
            coef[r2] = alphas[r2] * y[r2];
        }
    }
}

// ---------- fused RBF-SVM predict ----------
// pred_i = sum_j exp2( s_i + t_j + (2*g*log2e) * <x_i, xt_j> ) * coef_j + b
__launch_bounds__(256, 2)
__global__ void svm_main_kernel(const unsigned short* __restrict__ Abf,
                                const unsigned short* __restrict__ Bbf,
                                const float* __restrict__ srow,
                                const float* __restrict__ tcol,
                                const float* __restrict__ coef,
                                float* __restrict__ out,
                                int M) {
    __shared__ char As[BM * D * 2];    // 64 KiB: full-K A panel, swizzled image
    __shared__ char Bs[BN * BK * 2];   // 16 KiB: one B k-tile, swizzled image

    const int tid = threadIdx.x;
    const int w   = tid >> 6;          // wave 0..3
    const int l   = tid & 63;
    const int wr  = w >> 1;            // 2x2 wave grid, each wave owns 64x64
    const int wc  = w & 1;
    const int hi  = l >> 4;            // 0..3
    const int lo  = l & 15;
    const int row0  = blockIdx.x * BM;
    const int jspan = M / JSPLIT;      // 512
    const int jbase = blockIdx.y * jspan;

    // ---- stage A panel once: LDS linear dest, inverse-swizzled global src ----
    {
        const char* Ab = (const char*)Abf + (size_t)row0 * 512;
        #pragma unroll
        for (int c = 0; c < 16; ++c) {
            int x   = c * 4096 + tid * 16;           // linear LDS byte offset
            int row = x >> 9;                        // 512 B per row
            int src = row * 512 + ((x & 511) ^ ((row & 7) << 4));
            gload16(As + c * 4096 + w * 1024, Ab + src);
        }
    }

    // per-lane row constants (row = row0 + wr*64 + mi*16 + hi*4 + r)
    float sreg[4][4];
    #pragma unroll
    for (int mi = 0; mi < 4; ++mi)
        #pragma unroll
        for (int r = 0; r < 4; ++r)
            sreg[mi][r] = srow[row0 + wr * 64 + mi * 16 + hi * 4 + r];

    float partial[4][4];
    #pragma unroll
    for (int mi = 0; mi < 4; ++mi)
        #pragma unroll
        for (int r = 0; r < 4; ++r) partial[mi][r] = 0.0f;

    const float K2G = 2.0f * GAMMA_ * LOG2E_;
    const int JT = jspan / BN;   // 4 j-tiles per block

    for (int jt = 0; jt < JT; ++jt) {
        f32x4 acc[4][4];
        #pragma unroll
        for (int mi = 0; mi < 4; ++mi)
            #pragma unroll
            for (int ni = 0; ni < 4; ++ni) {
                f32x4 z = {0.f, 0.f, 0.f, 0.f};
                acc[mi][ni] = z;
            }

        #pragma unroll
        for (int kt = 0; kt < D / BK; ++kt) {    // 4 k-tiles
            __syncthreads();   // previous B reads done before overwrite
            {   // ---- stage B k-tile ----
                const char* Bb = (const char*)Bbf;
                #pragma unroll
                for (int c = 0; c < 4; ++c) {
                    int x   = c * 4096 + tid * 16;
                    int col = x >> 7;                // 128 B per col-row
                    int src = (jbase + jt * BN + col) * 512 + kt * 128
                            + ((x & 127) ^ ((col & 7) << 4));
                    gload16(Bs + c * 4096 + w * 1024, Bb + src);
                }
            }
            __syncthreads();

            #pragma unroll
            for (int ks = 0; ks < 2; ++ks) {
                const int kg = kt * 2 + ks;          // global K chunk (32 elems)
                bf16x8 a[4], bb[4];
                #pragma unroll
                for (int mi = 0; mi < 4; ++mi) {
                    int row = wr * 64 + mi * 16 + lo;
                    int off = row * 512 + kg * 64 + hi * 16;
                    off ^= (row & 7) << 4;
                    a[mi] = *(const bf16x8*)(As + off);
                }
                #pragma unroll
                for (int ni = 0; ni < 4; ++ni) {
                    int col = wc * 64 + ni * 16 + lo;
                    int off = col * 128 + ks * 64 + hi * 16;
                    off ^= (col & 7) << 4;
                    bb[ni] = *(const bf16x8*)(Bs + off);
                }
                #pragma unroll
                for (int mi = 0; mi < 4; ++mi)
                    #pragma unroll
                    for (int ni = 0; ni < 4; ++ni)
                        acc[mi][ni] = __builtin_amdgcn_mfma_f32_16x16x32_bf16(
                            a[mi], bb[ni], acc[mi][ni], 0, 0, 0);
            }
        }

        // ---- fused epilogue: exp + weighted row-accumulate ----
        #pragma unroll
        for (int ni = 0; ni < 4; ++ni) {
            int colg = jbase + jt * BN + wc * 64 + ni * 16 + lo;
            float t  = tcol[colg];
            float cf = coef[colg];
            #pragma unroll
            for (int mi = 0; mi < 4; ++mi) {
                #pragma unroll
                for (int r = 0; r < 4; ++r) {
                    float arg = fmaf(acc[mi][ni][r], K2G, sreg[mi][r] + t);
                    float p = __builtin_amdgcn_exp2f(arg);
                    partial[mi][r] = fmaf(p, cf, partial[mi][r]);
                }
            }
        }
    }

    // ---- reduce across 16 lanes per row, then one atomicAdd per row ----
    #pragma unroll
    for (int mi = 0; mi < 4; ++mi) {
        #pragma unroll
        for (int r = 0; r < 4; ++r) {
            float v = partial[mi][r];
            v += __shfl_xor(v, 1);
            v += __shfl_xor(v, 2);
            v += __shfl_xor(v, 4);
            v += __shfl_xor(v, 8);
            if (lo == 0) {
                int rowg = row0 + wr * 64 + mi * 16 + hi * 4 + r;
                atomicAdd(&out[rowg], v);
            }
        }
    }
}

// ---------- launcher ----------
extern "C" void kernel_launch(void* const* d_in, const int* in_sizes, int n_in,
                              void* d_out, int out_size, void* d_ws, size_t ws_size,
                              hipStream_t stream) {
    const float* X      = (const float*)d_in[0];
    const float* Xt     = (const float*)d_in[1];
    const float* alphas = (const float*)d_in[2];
    const float* y      = (const float*)d_in[3];
    const float* b      = (const float*)d_in[4];
    float* out = (float*)d_out;

    const int N = in_sizes[0] / D;   // 8192
    const int M = in_sizes[1] / D;   // 8192

    // workspace: bf16 X | bf16 Xt | srow[N] | tcol[M] | coef[M]
    char* ws = (char*)d_ws;
    unsigned short* Abf = (unsigned short*)ws;
    unsigned short* Bbf = Abf + (size_t)N * D;
    float* srow = (float*)(Bbf + (size_t)M * D);
    float* tcol = srow + N;
    float* coef = tcol + M;

    prep_all_kernel<<<(N + M) / 4, 256, 0, stream>>>(X, Xt, alphas, y, b,
                                                     Abf, Bbf, srow, tcol, coef,
                                                     out, N, M);

    dim3 grid(N / BM, JSPLIT);
    svm_main_kernel<<<grid, 256, 0, stream>>>(Abf, Bbf, srow, tcol, coef, out, M);
}